// Round 3
// baseline (271.472 us; speedup 1.0000x reference)
//
#include <hip/hip_runtime.h>
#include <stdint.h>
#include <math.h>

typedef unsigned int u32;
typedef __bf16 bf16x8 __attribute__((ext_vector_type(8)));
typedef float  f32x4  __attribute__((ext_vector_type(4)));
typedef float  f32x16 __attribute__((ext_vector_type(16)));
typedef unsigned int u32x4 __attribute__((ext_vector_type(4)));
typedef unsigned short u16x4 __attribute__((ext_vector_type(4)));
typedef unsigned short u16x8 __attribute__((ext_vector_type(8)));

#define DEV __device__ __forceinline__

DEV unsigned short f2b(float f) {
  u32 x = __builtin_bit_cast(u32, f);
  u32 r = (x + 0x7fffu + ((x >> 16) & 1u)) >> 16;
  return (unsigned short)r;
}
DEV float b2f(unsigned short u) { return __builtin_bit_cast(float, ((u32)u) << 16); }

DEV u32 cvtpk_bf16(float lo, float hi) {
  u32 r;
  asm("v_cvt_pk_bf16_f32 %0, %1, %2" : "=v"(r) : "v"(lo), "v"(hi));
  return r;
}
DEV void pl32swap(u32& a, u32& b) {
  asm("v_permlane32_swap_b32 %0, %1" : "+v"(a), "+v"(b));
}

// async global->LDS, 16B per lane. LDS dest = wave-uniform base + lane*16.
DEV void gl2lds16(const void* g, void* l) {
  __builtin_amdgcn_global_load_lds((const __attribute__((address_space(1))) u32*)g,
                                   (__attribute__((address_space(3))) u32*)l, 16, 0, 0);
}

// ---------------- small prep kernels ----------------

__global__ void rope_tables_k(float* __restrict__ ct, float* __restrict__ st) {
  int s = blockIdx.x;          // 0..2047
  int d = threadIdx.x;         // 0..63
  float inv = powf(10000.0f, -(float)d / 64.0f);
  float a = (float)s * inv;
  ct[s * 64 + d] = cosf(a);
  st[s * 64 + d] = sinf(a);
}

__global__ void cvt4_k(const float* __restrict__ in, unsigned short* __restrict__ out, int n4) {
  int i = blockIdx.x * blockDim.x + threadIdx.x;
  if (i >= n4) return;
  float4 v = ((const float4*)in)[i];
  u16x4 r = { f2b(v.x), f2b(v.y), f2b(v.z), f2b(v.w) };
  *(u16x4*)(out + (size_t)i * 4) = r;
}

// W [K][N] f32 -> Wt [N][K] bf16
__global__ void tcvt_k(const float* __restrict__ in, unsigned short* __restrict__ out,
                       int Kdim, int Ndim) {
  __shared__ float t[32][33];
  int n0 = blockIdx.x * 32, k0 = blockIdx.y * 32;
  int tx = threadIdx.x, ty = threadIdx.y;  // 32 x 8
  for (int i = ty; i < 32; i += 8) t[i][tx] = in[(size_t)(k0 + i) * Ndim + n0 + tx];
  __syncthreads();
  for (int i = ty; i < 32; i += 8)
    out[(size_t)(n0 + i) * Kdim + k0 + tx] = f2b(t[tx][i]);
}

// vectorized RoPE: each thread handles 8 d-values (pair d, d+64), 16B loads
template <bool SC>
__global__ void rope8_k(unsigned short* __restrict__ p, const float* __restrict__ ct,
                        const float* __restrict__ st, int total) {
  int i = blockIdx.x * blockDim.x + threadIdx.x;
  if (i >= total) return;
  int j = i & 7;               // which 8-wide d block in [0,64)
  int s = (i >> 3) & 2047;
  int bh = i >> 14;
  size_t base = ((size_t)bh * 2048 + s) * 128 + (j << 3);
  u16x8 a = *(const u16x8*)(p + base);
  u16x8 b = *(const u16x8*)(p + base + 64);
  const float* cp = ct + s * 64 + (j << 3);
  const float* sp = st + s * 64 + (j << 3);
  u16x8 oa, ob;
#pragma unroll
  for (int e = 0; e < 8; ++e) {
    float x1 = b2f(a[e]), x2 = b2f(b[e]);
    float c = cp[e], sn = sp[e];
    float o1 = x1 * c - x2 * sn;
    float o2 = x2 * c + x1 * sn;
    if (SC) { o1 *= 0.08838834764831845f; o2 *= 0.08838834764831845f; }
    oa[e] = f2b(o1);
    ob[e] = f2b(o2);
  }
  *(u16x8*)(p + base) = oa;
  *(u16x8*)(p + base + 64) = ob;
}

// ---------------- GEMM 256x256 tile, counted-vmcnt ring pipeline ----------------
// C = A * Bt^T. A [M][K] bf16, Bt [N][K] bf16. 8 waves (2M x 4N), 512 threads.
// LDS: per operand 4 slots of [256 rows][32 cols] bf16 (K-halves); phase s
// computes slot s&3 while staging K-half s+3 into slot (s+3)&3 = (s-1)&3
// (whose reads finished a barrier ago -> race-free). vmcnt(8) per phase keeps
// 2 half-stages in flight across the barrier (never drains to 0 mid-loop).
// MODE 0: fp32 out[row*Ndim+col]
// MODE 3: fused QKV epilogue (Q/K [B][h][S][128], V transposed [B][h][128][S])
template <int MODE>
__global__ __launch_bounds__(512, 2) void gemm256_k(
    const unsigned short* __restrict__ A, const unsigned short* __restrict__ Bt,
    float* __restrict__ outF,
    unsigned short* __restrict__ outQ, unsigned short* __restrict__ outK,
    unsigned short* __restrict__ outV,
    const float* __restrict__ bq_, const float* __restrict__ bk_,
    const float* __restrict__ bv_, int Ndim, int Kdim) {
  __shared__ alignas(16) unsigned short Al[4 * 256 * 32];  // 64 KiB
  __shared__ alignas(16) unsigned short Bl[4 * 256 * 32];  // 64 KiB

  const int tid = threadIdx.x, lane = tid & 63, wid = tid >> 6;
  const int wr = wid >> 2, wc = wid & 3;
  const int row0 = blockIdx.y << 8, col0 = blockIdx.x << 8;
  const int cl = lane & 15, g = lane >> 4;
  const int NPH = Kdim >> 5;        // 64 for K=2048

  f32x4 acc[8][4];
#pragma unroll
  for (int m = 0; m < 8; ++m)
#pragma unroll
    for (int n = 0; n < 4; ++n) acc[m][n] = (f32x4){0.f, 0.f, 0.f, 0.f};

  // stage K-half s (A and B): 16KB each; 2 gl2lds16 per thread per operand
  auto stage = [&](int s) {
    const int slot = (s & 3) << 13;      // *8192 u16
    const int kc = s << 5;
#pragma unroll
    for (int i = 0; i < 2; ++i) {
      int c = wid + (i << 3);            // chunk 0..15 = 16 rows x 64B
      int row = (c << 4) + (lane >> 2);
      int sl = (lane & 3) ^ (row & 3);
      gl2lds16(A + ((size_t)(row0 + row) * Kdim + kc + (sl << 3)),
               &Al[slot + (c << 9) + (lane << 3)]);
    }
#pragma unroll
    for (int i = 0; i < 2; ++i) {
      int c = wid + (i << 3);
      int row = (c << 4) + (lane >> 2);
      int sl = (lane & 3) ^ (row & 3);
      gl2lds16(Bt + ((size_t)(col0 + row) * Kdim + kc + (sl << 3)),
               &Bl[slot + (c << 9) + (lane << 3)]);
    }
  };

  // phase s: ds_read fragments of slot s&3, optionally stage s+3, 32 MFMA
  auto phase = [&](int s, bool do_stage) {
    const int slot = (s & 3) << 13;
    bf16x8 af[8], bfr[4];
#pragma unroll
    for (int m = 0; m < 8; ++m) {
      int row = (wr << 7) + (m << 4) + cl;
      af[m] = *(const bf16x8*)&Al[slot + (row << 5) + (((g ^ (row & 3))) << 3)];
    }
#pragma unroll
    for (int n = 0; n < 4; ++n) {
      int row = (wc << 6) + (n << 4) + cl;
      bfr[n] = *(const bf16x8*)&Bl[slot + (row << 5) + (((g ^ (row & 3))) << 3)];
    }
    if (do_stage) stage(s + 3);
    __builtin_amdgcn_s_setprio(1);
#pragma unroll
    for (int m = 0; m < 8; ++m)
#pragma unroll
      for (int n = 0; n < 4; ++n)
        acc[m][n] = __builtin_amdgcn_mfma_f32_16x16x32_bf16(af[m], bfr[n], acc[m][n], 0, 0, 0);
    __builtin_amdgcn_s_setprio(0);
  };

  // prologue: 3 half-stages in flight, wait until slot0 landed (8 = 2 stages)
  stage(0); stage(1); stage(2);
  asm volatile("s_waitcnt vmcnt(8)" ::: "memory");
  __builtin_amdgcn_s_barrier();
  __builtin_amdgcn_sched_barrier(0);

  int s = 0;
  for (; s + 3 < NPH; ++s) {
    phase(s, true);
    asm volatile("s_waitcnt vmcnt(8)" ::: "memory");
    __builtin_amdgcn_s_barrier();
    __builtin_amdgcn_sched_barrier(0);
  }
  // tail: NPH-3, NPH-2, NPH-1 (no staging; drain 4 -> 0 -> none)
  phase(s, false);
  asm volatile("s_waitcnt vmcnt(4)" ::: "memory");
  __builtin_amdgcn_s_barrier();
  __builtin_amdgcn_sched_barrier(0);
  ++s;
  phase(s, false);
  asm volatile("s_waitcnt vmcnt(0)" ::: "memory");
  __builtin_amdgcn_s_barrier();
  __builtin_amdgcn_sched_barrier(0);
  ++s;
  phase(s, false);

  // epilogue
#pragma unroll
  for (int m = 0; m < 8; ++m) {
    int rbase = row0 + (wr << 7) + (m << 4) + (g << 2);
#pragma unroll
    for (int n = 0; n < 4; ++n) {
      int col = col0 + (wc << 6) + (n << 4) + cl;
#pragma unroll
      for (int r = 0; r < 4; ++r) {
        float v = acc[m][n][r];
        int rr = rbase + r;
        if constexpr (MODE == 0) {
          outF[(size_t)rr * Ndim + col] = v;
        } else {  // MODE 3
          int bb = rr >> 11, ss = rr & 2047;
          if (col < 2048) {
            int hh = col >> 7, d = col & 127;
            outQ[((((size_t)bb << 4) + hh) * 2048 + ss) * 128 + d] = f2b(v + bq_[col]);
          } else if (col < 2560) {
            int c2 = col - 2048, kk = c2 >> 7, d = c2 & 127;
            outK[((((size_t)bb << 2) + kk) * 2048 + ss) * 128 + d] = f2b(v + bk_[c2]);
          } else {
            int c2 = col - 2560, kk = c2 >> 7, d = c2 & 127;
            outV[((((size_t)bb << 2) + kk) * 128 + d) * 2048 + ss] = f2b(v + bv_[c2]);
          }
        }
      }
    }
  }
}

// ---------------- flash attention: swapped QK^T, 32x32x16 MFMA ----------------
// Qb [B][16][S][128] (pre-scaled, RoPE'd) bf16
// Kb [B][4][S][128] (RoPE'd) bf16, Vt [B][4][128][S] bf16
// AO [B*S][2048] bf16.  256 threads = 4 waves x 32 q-rows, KVBLK=64.
__global__ __launch_bounds__(256, 2) void attn2_k(
    const unsigned short* __restrict__ Qb, const unsigned short* __restrict__ Kb,
    const unsigned short* __restrict__ Vt, unsigned short* __restrict__ AO) {
  __shared__ alignas(16) unsigned short Ks[2][64 * 128];   // [kv][d], slot^=(row&15)
  __shared__ alignas(16) unsigned short Vs[2][128 * 64];   // [d][kv], slot^=(row&7)

  const int tid = threadIdx.x, lane = tid & 63, wid = tid >> 6;
  const int hw = blockIdx.x;
  const int work = ((hw & 7) << 6) | (hw >> 3);
  const int qblk = work & 15, bh = work >> 4;
  const int b = bh >> 4, h = bh & 15, kvh = h >> 2;
  const int q0 = qblk << 7;
  const int cl = lane & 31, hi = lane >> 5;

  const unsigned short* Qp = Qb + ((size_t)(b * 16 + h) << 11) * 128;
  const unsigned short* Kp = Kb + ((size_t)(b * 4 + kvh) << 11) * 128;
  const unsigned short* Vp = Vt + ((size_t)(b * 4 + kvh) << 7) * 2048;

  const int qrow = q0 + (wid << 5) + cl;
  bf16x8 qf[8];
#pragma unroll
  for (int c = 0; c < 8; ++c)
    qf[c] = *(const bf16x8*)(Qp + (size_t)qrow * 128 + (c << 4) + (hi << 3));

  f32x16 o[4];
#pragma unroll
  for (int dt = 0; dt < 4; ++dt)
#pragma unroll
    for (int r = 0; r < 16; ++r) o[dt][r] = 0.f;
  float m = -3e38f, l = 0.f;

  auto stage = [&](int t, int buf) {
    const int kv0 = t << 6;
#pragma unroll
    for (int i = 0; i < 4; ++i) {   // K: wave stages 16 rows x 256B
      int row = (wid << 4) + (i << 2) + (lane >> 4);
      int sl = (lane & 15) ^ (row & 15);
      gl2lds16(Kp + ((size_t)(kv0 + row) << 7) + (sl << 3),
               &Ks[buf][(wid << 11) + (i << 9) + (lane << 3)]);
    }
#pragma unroll
    for (int i = 0; i < 4; ++i) {   // V^T: wave stages 32 rows x 128B
      int row = (wid << 5) + (i << 3) + (lane >> 3);
      int sl = (lane & 7) ^ (row & 7);
      gl2lds16(Vp + ((size_t)row << 11) + kv0 + (sl << 3),
               &Vs[buf][(wid << 11) + (i << 9) + (lane << 3)]);
    }
  };

  auto pack8 = [&](float a0, float a1, float a2, float a3,
                   float a4, float a5, float a6, float a7) -> u32x4 {
    u32 x0 = cvtpk_bf16(a0, a1);
    u32 y0 = cvtpk_bf16(a4, a5);
    u32 x1 = cvtpk_bf16(a2, a3);
    u32 y1 = cvtpk_bf16(a6, a7);
    pl32swap(x0, y0);
    pl32swap(x1, y1);
    return (u32x4){x0, x1, y0, y1};
  };

  stage(0, 0);
  __syncthreads();

  for (int t = 0; t < 32; ++t) {
    const int buf = t & 1;
    if (t + 1 < 32) stage(t + 1, buf ^ 1);

    f32x16 s0, s1;
#pragma unroll
    for (int r = 0; r < 16; ++r) { s0[r] = 0.f; s1[r] = 0.f; }
#pragma unroll
    for (int c = 0; c < 8; ++c) {
      int sl0 = ((c << 1) + hi) ^ (cl & 15);
      bf16x8 kf0 = *(const bf16x8*)&Ks[buf][(cl << 7) + (sl0 << 3)];
      s0 = __builtin_amdgcn_mfma_f32_32x32x16_bf16(kf0, qf[c], s0, 0, 0, 0);
    }
#pragma unroll
    for (int c = 0; c < 8; ++c) {
      int row = 32 + cl;
      int sl1 = ((c << 1) + hi) ^ (row & 15);
      bf16x8 kf1 = *(const bf16x8*)&Ks[buf][(row << 7) + (sl1 << 3)];
      s1 = __builtin_amdgcn_mfma_f32_32x32x16_bf16(kf1, qf[c], s1, 0, 0, 0);
    }

    float mx = s0[0];
#pragma unroll
    for (int r = 1; r < 16; ++r) mx = fmaxf(mx, s0[r]);
#pragma unroll
    for (int r = 0; r < 16; ++r) mx = fmaxf(mx, s1[r]);
    mx = fmaxf(mx, __shfl_xor(mx, 32));

    if (!__all(mx <= m + 8.0f)) {
      float mn = fmaxf(m, mx);
      float al = __expf(m - mn);
      m = mn;
      l *= al;
#pragma unroll
      for (int dt = 0; dt < 4; ++dt)
#pragma unroll
        for (int r = 0; r < 16; ++r) o[dt][r] *= al;
    }

    float sum = 0.f;
#pragma unroll
    for (int r = 0; r < 16; ++r) { s0[r] = __expf(s0[r] - m); sum += s0[r]; }
#pragma unroll
    for (int r = 0; r < 16; ++r) { s1[r] = __expf(s1[r] - m); sum += s1[r]; }
    l += sum;

    u32x4 w0 = pack8(s0[0], s0[1], s0[2], s0[3], s0[4], s0[5], s0[6], s0[7]);
    u32x4 w1 = pack8(s0[8], s0[9], s0[10], s0[11], s0[12], s0[13], s0[14], s0[15]);
    u32x4 w2 = pack8(s1[0], s1[1], s1[2], s1[3], s1[4], s1[5], s1[6], s1[7]);
    u32x4 w3 = pack8(s1[8], s1[9], s1[10], s1[11], s1[12], s1[13], s1[14], s1[15]);
    bf16x8 pa0 = __builtin_bit_cast(bf16x8, w0);
    bf16x8 pa1 = __builtin_bit_cast(bf16x8, w1);
    bf16x8 pa2 = __builtin_bit_cast(bf16x8, w2);
    bf16x8 pa3 = __builtin_bit_cast(bf16x8, w3);

#pragma unroll
    for (int dt = 0; dt < 4; ++dt) {
      int row = (dt << 5) + cl;
      int sb = row << 6;
      int rx = row & 7;
      bf16x8 vf0 = *(const bf16x8*)&Vs[buf][sb + (((hi) ^ rx) << 3)];
      o[dt] = __builtin_amdgcn_mfma_f32_32x32x16_bf16(vf0, pa0, o[dt], 0, 0, 0);
      bf16x8 vf1 = *(const bf16x8*)&Vs[buf][sb + (((2 + hi) ^ rx) << 3)];
      o[dt] = __builtin_amdgcn_mfma_f32_32x32x16_bf16(vf1, pa1, o[dt], 0, 0, 0);
      bf16x8 vf2 = *(const bf16x8*)&Vs[buf][sb + (((4 + hi) ^ rx) << 3)];
      o[dt] = __builtin_amdgcn_mfma_f32_32x32x16_bf16(vf2, pa2, o[dt], 0, 0, 0);
      bf16x8 vf3 = *(const bf16x8*)&Vs[buf][sb + (((6 + hi) ^ rx) << 3)];
      o[dt] = __builtin_amdgcn_mfma_f32_32x32x16_bf16(vf3, pa3, o[dt], 0, 0, 0);
    }
    __syncthreads();
  }

  float inv = 1.0f / (l + __shfl_xor(l, 32));
  unsigned short* dst = AO + ((size_t)(b * 2048 + qrow) * 2048) + (h << 7);
#pragma unroll
  for (int dt = 0; dt < 4; ++dt) {
#pragma unroll
    for (int rq = 0; rq < 4; ++rq) {
      int d0 = (dt << 5) + (rq << 3) + (hi << 2);
      u16x4 pk = { f2b(o[dt][(rq << 2) + 0] * inv), f2b(o[dt][(rq << 2) + 1] * inv),
                   f2b(o[dt][(rq << 2) + 2] * inv), f2b(o[dt][(rq << 2) + 3] * inv) };
      *(u16x4*)(dst + d0) = pk;
    }
  }
}

// ---------------- launch ----------------
extern "C" void kernel_launch(void* const* d_in, const int* in_sizes, int n_in,
                              void* d_out, int out_size, void* d_ws, size_t ws_size,
                              hipStream_t stream) {
  const float* X  = (const float*)d_in[0];
  const float* Wq = (const float*)d_in[1];
  const float* bq = (const float*)d_in[2];
  const float* Wk = (const float*)d_in[3];
  const float* bk = (const float*)d_in[4];
  const float* Wv = (const float*)d_in[5];
  const float* bv = (const float*)d_in[6];
  const float* Wo = (const float*)d_in[7];
  float* out = (float*)d_out;

  char* ws = (char*)d_ws;
  size_t off = 0;
  auto alloc = [&](size_t bytes) {
    char* p = ws + off;
    off += (bytes + 255) & ~(size_t)255;
    return p;
  };
  unsigned short* Xb    = (unsigned short*)alloc(4096ull * 2048 * 2);
  unsigned short* Wtall = (unsigned short*)alloc(3072ull * 2048 * 2);  // [Wq|Wk|Wv]^T
  unsigned short* Wot   = (unsigned short*)alloc(2048ull * 2048 * 2);
  unsigned short* Qb    = (unsigned short*)alloc(2ull * 16 * 2048 * 128 * 2);
  unsigned short* Kb    = (unsigned short*)alloc(2ull * 4 * 2048 * 128 * 2);
  unsigned short* Vt    = (unsigned short*)alloc(2ull * 4 * 128 * 2048 * 2);
  unsigned short* AO    = (unsigned short*)alloc(4096ull * 2048 * 2);
  float* ctab = (float*)alloc(2048ull * 64 * 4);
  float* stab = (float*)alloc(2048ull * 64 * 4);

  rope_tables_k<<<dim3(2048), dim3(64), 0, stream>>>(ctab, stab);
  cvt4_k<<<dim3(8192), dim3(256), 0, stream>>>(X, Xb, 2097152);
  tcvt_k<<<dim3(64, 64), dim3(32, 8), 0, stream>>>(Wq, Wtall, 2048, 2048);
  tcvt_k<<<dim3(16, 64), dim3(32, 8), 0, stream>>>(Wk, Wtall + 2048ull * 2048, 2048, 512);
  tcvt_k<<<dim3(16, 64), dim3(32, 8), 0, stream>>>(Wv, Wtall + 2560ull * 2048, 2048, 512);
  tcvt_k<<<dim3(64, 64), dim3(32, 8), 0, stream>>>(Wo, Wot, 2048, 2048);

  // fused QKV projection: M=4096, N=3072, K=2048
  gemm256_k<3><<<dim3(12, 16), dim3(512), 0, stream>>>(
      Xb, Wtall, nullptr, Qb, Kb, Vt, bq, bk, bv, 3072, 2048);

  rope8_k<true><<<dim3(2048), dim3(256), 0, stream>>>(Qb, ctab, stab, 524288);
  rope8_k<false><<<dim3(512), dim3(256), 0, stream>>>(Kb, ctab, stab, 131072);

  attn2_k<<<dim3(512), dim3(256), 0, stream>>>(Qb, Kb, Vt, AO);

  // O projection: M=4096, N=2048, K=2048, fp32 out
  gemm256_k<0><<<dim3(8, 16), dim3(512), 0, stream>>>(
      AO, Wot, out, nullptr, nullptr, nullptr, nullptr, nullptr, nullptr, 2048, 2048);
}